// Round 1
// baseline (1727.358 us; speedup 1.0000x reference)
//
#include <hip/hip_runtime.h>

constexpr int N   = 100000;
constexpr int E   = 1600000;
constexpr int FIN = 9;
constexpr int OUTF = 6;
constexpr int G   = 1024;

__device__ __forceinline__ void atomAdd(float* p, float v) { unsafeAtomicAdd(p, v); }

// ---- layer-0 scatter: A[dst,0..9) += x[src,0..9) * w ----
__global__ __launch_bounds__(256) void scatter9(const float* __restrict__ x,
    const int* __restrict__ src, const int* __restrict__ dst,
    const float* __restrict__ ew, float* __restrict__ A)
{
    int i = blockIdx.x * blockDim.x + threadIdx.x;
    int stride = gridDim.x * blockDim.x;
    for (int e = i; e < E; e += stride) {
        int s = src[e], d = dst[e];
        float w = ew[e];
        const float* xr = x + s * FIN;
        float* ar = A + d * FIN;
#pragma unroll
        for (int f = 0; f < FIN; f++) atomAdd(ar + f, xr[f] * w);
    }
}

// ---- 64-wide scatter: one wave per edge, lane = feature ----
__global__ __launch_bounds__(256) void scatter64(const float* __restrict__ Hin,
    const int* __restrict__ src, const int* __restrict__ dst,
    const float* __restrict__ ew, float* __restrict__ A)
{
    int lane = threadIdx.x & 63;
    int wave = (blockIdx.x * blockDim.x + threadIdx.x) >> 6;
    int nwaves = (gridDim.x * blockDim.x) >> 6;
    for (int e = wave; e < E; e += nwaves) {
        int s = src[e], d = dst[e];
        float w = ew[e];
        float v = Hin[(size_t)s * 64 + lane] * w;
        atomAdd(&A[(size_t)d * 64 + lane], v);
    }
}

// ---- dense: H = Agg@Wrel + Xin@Wroot + b.  W columns in VGPRs, rows via
// wave-uniform broadcast loads.  MODE 0: store + BN stats.  MODE 1: pool atomics.
template<int K, int MODE>
__global__ __launch_bounds__(256) void dense(const float* __restrict__ Agg,
    const float* __restrict__ Xin, const float* __restrict__ Wrel,
    const float* __restrict__ Wroot, const float* __restrict__ bias,
    float* __restrict__ Hout, float* __restrict__ stats,
    const int* __restrict__ batch, float* __restrict__ pool)
{
    int t = threadIdx.x;
    int j = t & 63;
    int nl = __builtin_amdgcn_readfirstlane(t >> 6);  // wave-uniform sub-tile id
    float wrel[K], wroot[K];
#pragma unroll
    for (int k = 0; k < K; k++) { wrel[k] = Wrel[k * 64 + j]; wroot[k] = Wroot[k * 64 + j]; }
    float bj = bias[j];
    float s1 = 0.f, s2 = 0.f;
    const int ntiles = N / 4;                  // 25000, exact
    for (int tile = blockIdx.x; tile < ntiles; tile += gridDim.x) {
        int n = tile * 4 + nl;
        const float* ra = Agg + (size_t)n * K; // wave-uniform base -> broadcast loads
        const float* rx = Xin + (size_t)n * K;
        float acc = bj;
#pragma unroll
        for (int k = 0; k < K; k++) {
            acc = fmaf(ra[k], wrel[k], acc);
            acc = fmaf(rx[k], wroot[k], acc);
        }
        if constexpr (MODE == 0) {
            Hout[(size_t)n * 64 + j] = acc;    // may alias Xin: store depends on all row loads
            s1 += acc;
            s2 += acc * acc;
        } else {
            int g = batch[n];
            atomAdd(&pool[g * 64 + j], acc);
        }
    }
    if constexpr (MODE == 0) {
        __shared__ float sred[256];
        sred[t] = s1;
        __syncthreads();
        if (t < 64) atomAdd(&stats[t], sred[t] + sred[t + 64] + sred[t + 128] + sred[t + 192]);
        __syncthreads();
        sred[t] = s2;
        __syncthreads();
        if (t < 64) atomAdd(&stats[64 + t], sred[t] + sred[t + 64] + sred[t + 128] + sred[t + 192]);
    }
}

// ---- BN finalize + ReLU, in place, float4 ----
__global__ __launch_bounds__(256) void bn_relu(float4* __restrict__ H4,
    const float* __restrict__ stats, const float* __restrict__ gam,
    const float* __restrict__ bet)
{
    int i = blockIdx.x * blockDim.x + threadIdx.x;   // over N*16 exactly
    constexpr float invN = 1.0f / (float)N;
    int j0 = (i & 15) * 4;
    float4 h = H4[i];
    float r[4] = {h.x, h.y, h.z, h.w};
#pragma unroll
    for (int c = 0; c < 4; c++) {
        int j = j0 + c;
        float m = stats[j] * invN;
        float v = stats[64 + j] * invN - m * m;
        float sc = gam[j] * rsqrtf(v + 1e-5f);
        float sh = bet[j] - m * sc;
        r[c] = fmaxf(fmaf(r[c], sc, sh), 0.f);
    }
    H4[i] = make_float4(r[0], r[1], r[2], r[3]);
}

// ---- head: mean-pool finalize (counts via binary search) + 2-layer MLP ----
__global__ __launch_bounds__(64) void head(const float* __restrict__ pool,
    const int* __restrict__ batch, const float* __restrict__ Wl1,
    const float* __restrict__ bl1, const float* __restrict__ Wl2,
    const float* __restrict__ bl2, float* __restrict__ out)
{
    int g = blockIdx.x;
    int t = threadIdx.x;
    __shared__ float sp[64];
    __shared__ float sz[64];
    __shared__ int scnt;
    if (t == 0) {
        int lo = 0, hi = N;
        while (lo < hi) { int m = (lo + hi) >> 1; if (batch[m] < g) lo = m + 1; else hi = m; }
        int lo2 = lo, hi2 = N;
        while (lo2 < hi2) { int m = (lo2 + hi2) >> 1; if (batch[m] < g + 1) lo2 = m + 1; else hi2 = m; }
        scnt = lo2 - lo;
    }
    __syncthreads();
    float cnt = fmaxf((float)scnt, 1.0f);
    sp[t] = pool[g * 64 + t] / cnt;
    __syncthreads();
    float acc = bl1[t];
#pragma unroll
    for (int k = 0; k < 64; k++) acc = fmaf(sp[k], Wl1[k * 64 + t], acc);
    sz[t] = fmaxf(acc, 0.f);
    __syncthreads();
    if (t < OUTF) {
        float o = bl2[t];
#pragma unroll
        for (int k = 0; k < 64; k++) o = fmaf(sz[k], Wl2[k * OUTF + t], o);
        out[g * OUTF + t] = o;
    }
}

extern "C" void kernel_launch(void* const* d_in, const int* in_sizes, int n_in,
                              void* d_out, int out_size, void* d_ws, size_t ws_size,
                              hipStream_t stream)
{
    const float* x     = (const float*)d_in[0];
    const int*   ei    = (const int*)d_in[1];
    const float* ew    = (const float*)d_in[2];
    const int*   batch = (const int*)d_in[3];
    const float* Wrel0 = (const float*)d_in[4];
    const float* Wroot0= (const float*)d_in[5];
    const float* b0    = (const float*)d_in[6];
    const float* Wrel1 = (const float*)d_in[7];
    const float* Wroot1= (const float*)d_in[8];
    const float* b1    = (const float*)d_in[9];
    const float* Wrel2 = (const float*)d_in[10];
    const float* Wroot2= (const float*)d_in[11];
    const float* b2    = (const float*)d_in[12];
    const float* g0    = (const float*)d_in[13];
    const float* be0   = (const float*)d_in[14];
    const float* g1    = (const float*)d_in[15];
    const float* be1   = (const float*)d_in[16];
    const float* Wl1   = (const float*)d_in[17];
    const float* bl1   = (const float*)d_in[18];
    const float* Wl2   = (const float*)d_in[19];
    const float* bl2   = (const float*)d_in[20];
    const int* srcI = ei;
    const int* dstI = ei + E;

    float* ws = (float*)d_ws;
    float* B0     = ws;                          // N*64
    float* B1     = ws + (size_t)N * 64;         // N*64
    float* stats0 = ws + (size_t)2 * N * 64;     // 128
    float* stats1 = stats0 + 128;                // 128
    float* pool   = stats1 + 128;                // G*64

    // zero agg0 region + stats/pool (ws is poisoned 0xAA before every call)
    hipMemsetAsync(B0, 0, (size_t)N * FIN * sizeof(float), stream);
    hipMemsetAsync(stats0, 0, (size_t)(256 + G * 64) * sizeof(float), stream);

    // layer 0
    scatter9<<<1024, 256, 0, stream>>>(x, srcI, dstI, ew, B0);
    dense<FIN, 0><<<1024, 256, 0, stream>>>(B0, x, Wrel0, Wroot0, b0, B1, stats0, nullptr, nullptr);
    bn_relu<<<N * 16 / 256, 256, 0, stream>>>((float4*)B1, stats0, g0, be0);

    // layer 1
    hipMemsetAsync(B0, 0, (size_t)N * 64 * sizeof(float), stream);
    scatter64<<<2048, 256, 0, stream>>>(B1, srcI, dstI, ew, B0);
    dense<64, 0><<<1024, 256, 0, stream>>>(B0, B1, Wrel1, Wroot1, b1, B1, stats1, nullptr, nullptr);
    bn_relu<<<N * 16 / 256, 256, 0, stream>>>((float4*)B1, stats1, g1, be1);

    // layer 2 + fused pooling
    hipMemsetAsync(B0, 0, (size_t)N * 64 * sizeof(float), stream);
    scatter64<<<2048, 256, 0, stream>>>(B1, srcI, dstI, ew, B0);
    dense<64, 1><<<1024, 256, 0, stream>>>(B0, B1, Wrel2, Wroot2, b2, nullptr, nullptr, batch, pool);

    // head
    head<<<G, 64, 0, stream>>>(pool, batch, Wl1, bl1, Wl2, bl2, (float*)d_out);
}

// Round 2
// 1007.493 us; speedup vs baseline: 1.7145x; 1.7145x over previous
//
#include <hip/hip_runtime.h>

constexpr int N   = 100000;
constexpr int E   = 1600000;
constexpr int FIN = 9;
constexpr int OUTF = 6;
constexpr int G   = 1024;
constexpr int SCAN_B = 1024;
constexpr int NBLK = (N + SCAN_B - 1) / SCAN_B;   // 98

__device__ __forceinline__ void atomAddF(float* p, float v) { unsafeAtomicAdd(p, v); }

// ---- CSR build: histogram of dst ----
__global__ __launch_bounds__(256) void hist(const int* __restrict__ dst, int* __restrict__ deg)
{
    int i = blockIdx.x * blockDim.x + threadIdx.x, s = gridDim.x * blockDim.x;
    for (int e = i; e < E; e += s) atomicAdd(&deg[dst[e]], 1);
}

__global__ __launch_bounds__(SCAN_B) void blocksum(const int* __restrict__ deg, int* __restrict__ bsum)
{
    __shared__ int sm[SCAN_B];
    int t = threadIdx.x, idx = blockIdx.x * SCAN_B + t;
    sm[t] = (idx < N) ? deg[idx] : 0;
    __syncthreads();
    for (int o = SCAN_B / 2; o > 0; o >>= 1) { if (t < o) sm[t] += sm[t + o]; __syncthreads(); }
    if (t == 0) bsum[blockIdx.x] = sm[0];
}

__global__ void scanbsum(const int* __restrict__ bsum, int* __restrict__ boff)
{
    if (threadIdx.x == 0) {
        int acc = 0;
        for (int b = 0; b < NBLK; b++) { boff[b] = acc; acc += bsum[b]; }
    }
}

__global__ __launch_bounds__(SCAN_B) void scanwrite(const int* __restrict__ deg,
    const int* __restrict__ boff, int* __restrict__ ptr, int* __restrict__ pos)
{
    __shared__ int sm[SCAN_B];
    int t = threadIdx.x, idx = blockIdx.x * SCAN_B + t;
    int v = (idx < N) ? deg[idx] : 0;
    sm[t] = v;
    __syncthreads();
    for (int o = 1; o < SCAN_B; o <<= 1) {
        int add = (t >= o) ? sm[t - o] : 0;
        __syncthreads();
        sm[t] += add;
        __syncthreads();
    }
    int excl = sm[t] - v + boff[blockIdx.x];
    if (idx < N) { ptr[idx] = excl; pos[idx] = excl; }
    if (idx == N - 1) ptr[N] = excl + v;
}

__global__ __launch_bounds__(256) void fillcsr(const int* __restrict__ src, const int* __restrict__ dst,
    const float* __restrict__ ew, int* __restrict__ pos, int2* __restrict__ csr)
{
    int i = blockIdx.x * blockDim.x + threadIdx.x, s = gridDim.x * blockDim.x;
    for (int e = i; e < E; e += s) {
        int d = dst[e];
        int p = atomicAdd(&pos[d], 1);
        csr[p] = make_int2(src[e], __float_as_int(ew[e]));
    }
}

// ---- fused projection: P = Ain@Wrel ; Aout = Ain@Wroot + b (Aout may alias Ain) ----
template<int K>
__global__ __launch_bounds__(256) void proj(const float* Ain,
    const float* __restrict__ Wrel, const float* __restrict__ Wroot,
    const float* __restrict__ bias, float* __restrict__ P, float* Aout)
{
    int t = threadIdx.x, j = t & 63;
    int nl = __builtin_amdgcn_readfirstlane(t >> 6);   // wave-uniform sub-tile
    float wrel[K], wroot[K];
#pragma unroll
    for (int k = 0; k < K; k++) { wrel[k] = Wrel[k * 64 + j]; wroot[k] = Wroot[k * 64 + j]; }
    float bj = bias[j];
    const int ntiles = N / 4;   // exact
    for (int tile = blockIdx.x; tile < ntiles; tile += gridDim.x) {
        int n = tile * 4 + nl;
        float ap = 0.f, ar = bj;
        if constexpr (K == 64) {
            const float4* r4 = (const float4*)(Ain + (size_t)n * 64);
#pragma unroll
            for (int q = 0; q < 16; q++) {
                float4 v = r4[q];
                ap = fmaf(v.x, wrel[4*q+0], ap); ar = fmaf(v.x, wroot[4*q+0], ar);
                ap = fmaf(v.y, wrel[4*q+1], ap); ar = fmaf(v.y, wroot[4*q+1], ar);
                ap = fmaf(v.z, wrel[4*q+2], ap); ar = fmaf(v.z, wroot[4*q+2], ar);
                ap = fmaf(v.w, wrel[4*q+3], ap); ar = fmaf(v.w, wroot[4*q+3], ar);
            }
        } else {
            const float* r = Ain + (size_t)n * K;
#pragma unroll
            for (int k = 0; k < K; k++) {
                float h = r[k];
                ap = fmaf(h, wrel[k], ap);
                ar = fmaf(h, wroot[k], ar);
            }
        }
        P[(size_t)n * 64 + j] = ap;
        Aout[(size_t)n * 64 + j] = ar;    // all row loads precede store via data dep
    }
}

// ---- gather-aggregate: A[n] += sum_e w_e * P[src_e]  (wave per node, lane = feature) ----
template<int EPI>   // 0: write A + BN stats; 1: pool atomics (A unchanged)
__global__ __launch_bounds__(256) void gather(const float* __restrict__ P, float* A,
    const int2* __restrict__ csr, const int* __restrict__ ptr,
    float* __restrict__ stats, const int* __restrict__ batch, float* __restrict__ pool)
{
    int t = threadIdx.x, lane = t & 63;
    int wv = (blockIdx.x * blockDim.x + t) >> 6;
    int nw = (gridDim.x * blockDim.x) >> 6;
    float s1 = 0.f, s2 = 0.f;
    for (int n = wv; n < N; n += nw) {
        int beg = ptr[n], end = ptr[n + 1];
        float acc = A[(size_t)n * 64 + lane];   // root part already in place
        for (int base = beg; base < end; base += 64) {
            int m = end - base; if (m > 64) m = 64;
            int2 ed = (lane < m) ? csr[base + lane] : make_int2(0, 0);
            for (int jj = 0; jj < m; jj++) {
                int   s = __shfl(ed.x, jj, 64);
                float w = __int_as_float(__shfl(ed.y, jj, 64));
                acc = fmaf(w, P[(size_t)s * 64 + lane], acc);
            }
        }
        if constexpr (EPI == 0) {
            A[(size_t)n * 64 + lane] = acc;
            s1 += acc; s2 += acc * acc;
        } else {
            atomAddF(&pool[batch[n] * 64 + lane], acc);
        }
    }
    if constexpr (EPI == 0) {
        __shared__ float sred[256];
        sred[t] = s1; __syncthreads();
        if (t < 64) atomAddF(&stats[t], sred[t] + sred[t+64] + sred[t+128] + sred[t+192]);
        __syncthreads();
        sred[t] = s2; __syncthreads();
        if (t < 64) atomAddF(&stats[64 + t], sred[t] + sred[t+64] + sred[t+128] + sred[t+192]);
    }
}

// ---- BN finalize + ReLU, in place, float4 ----
__global__ __launch_bounds__(256) void bn_relu(float4* __restrict__ H4,
    const float* __restrict__ stats, const float* __restrict__ gam, const float* __restrict__ bet)
{
    int i = blockIdx.x * blockDim.x + threadIdx.x;   // over N*16 exactly
    constexpr float invN = 1.0f / (float)N;
    int j0 = (i & 15) * 4;
    float4 h = H4[i];
    float r[4] = {h.x, h.y, h.z, h.w};
#pragma unroll
    for (int c = 0; c < 4; c++) {
        int j = j0 + c;
        float m  = stats[j] * invN;
        float vv = stats[64 + j] * invN - m * m;
        float sc = gam[j] * rsqrtf(vv + 1e-5f);
        float sh = bet[j] - m * sc;
        r[c] = fmaxf(fmaf(r[c], sc, sh), 0.f);
    }
    H4[i] = make_float4(r[0], r[1], r[2], r[3]);
}

// ---- head: mean-pool finalize + 2-layer MLP ----
__global__ __launch_bounds__(64) void head(const float* __restrict__ pool,
    const int* __restrict__ batch, const float* __restrict__ Wl1, const float* __restrict__ bl1,
    const float* __restrict__ Wl2, const float* __restrict__ bl2, float* __restrict__ out)
{
    int g = blockIdx.x, t = threadIdx.x;
    __shared__ float sp[64];
    __shared__ float sz[64];
    __shared__ int scnt;
    if (t == 0) {
        int lo = 0, hi = N;
        while (lo < hi) { int m = (lo + hi) >> 1; if (batch[m] < g) lo = m + 1; else hi = m; }
        int lo2 = lo, hi2 = N;
        while (lo2 < hi2) { int m = (lo2 + hi2) >> 1; if (batch[m] < g + 1) lo2 = m + 1; else hi2 = m; }
        scnt = lo2 - lo;
    }
    __syncthreads();
    float cnt = fmaxf((float)scnt, 1.0f);
    sp[t] = pool[g * 64 + t] / cnt;
    __syncthreads();
    float acc = bl1[t];
#pragma unroll
    for (int k = 0; k < 64; k++) acc = fmaf(sp[k], Wl1[k * 64 + t], acc);
    sz[t] = fmaxf(acc, 0.f);
    __syncthreads();
    if (t < OUTF) {
        float o = bl2[t];
#pragma unroll
        for (int k = 0; k < 64; k++) o = fmaf(sz[k], Wl2[k * OUTF + t], o);
        out[g * OUTF + t] = o;
    }
}

extern "C" void kernel_launch(void* const* d_in, const int* in_sizes, int n_in,
                              void* d_out, int out_size, void* d_ws, size_t ws_size,
                              hipStream_t stream)
{
    const float* x     = (const float*)d_in[0];
    const int*   ei    = (const int*)d_in[1];
    const float* ew    = (const float*)d_in[2];
    const int*   batch = (const int*)d_in[3];
    const float* Wrel0 = (const float*)d_in[4];
    const float* Wroot0= (const float*)d_in[5];
    const float* b0    = (const float*)d_in[6];
    const float* Wrel1 = (const float*)d_in[7];
    const float* Wroot1= (const float*)d_in[8];
    const float* b1    = (const float*)d_in[9];
    const float* Wrel2 = (const float*)d_in[10];
    const float* Wroot2= (const float*)d_in[11];
    const float* b2    = (const float*)d_in[12];
    const float* g0    = (const float*)d_in[13];
    const float* be0   = (const float*)d_in[14];
    const float* g1    = (const float*)d_in[15];
    const float* be1   = (const float*)d_in[16];
    const float* Wl1   = (const float*)d_in[17];
    const float* bl1   = (const float*)d_in[18];
    const float* Wl2   = (const float*)d_in[19];
    const float* bl2   = (const float*)d_in[20];
    const int* srcI = ei;
    const int* dstI = ei + E;

    float* ws = (float*)d_ws;
    float* A      = ws;                              // N*64
    float* P      = A + (size_t)N * 64;              // N*64
    int2*  csr    = (int2*)(P + (size_t)N * 64);     // E pairs
    int*   ptr    = (int*)(csr + E);                 // N+1
    int*   pos    = ptr + N + 1;                     // N
    int*   deg    = pos + N;                         // N
    int*   bsum   = deg + N;                         // NBLK
    int*   boff   = bsum + NBLK;                     // NBLK
    float* stats0 = (float*)(boff + NBLK);           // 128
    float* stats1 = stats0 + 128;                    // 128
    float* pool   = stats1 + 128;                    // G*64

    hipMemsetAsync(deg, 0, (size_t)N * sizeof(int), stream);
    hipMemsetAsync(stats0, 0, (size_t)(256 + G * 64) * sizeof(float), stream);

    // ---- CSR build (by dst), reused by all 3 layers ----
    hist<<<1024, 256, 0, stream>>>(dstI, deg);
    blocksum<<<NBLK, SCAN_B, 0, stream>>>(deg, bsum);
    scanbsum<<<1, 64, 0, stream>>>(bsum, boff);
    scanwrite<<<NBLK, SCAN_B, 0, stream>>>(deg, boff, ptr, pos);
    fillcsr<<<1024, 256, 0, stream>>>(srcI, dstI, ew, pos, csr);

    // ---- layer 0 ----
    proj<FIN><<<1024, 256, 0, stream>>>(x, Wrel0, Wroot0, b0, P, A);
    gather<0><<<1024, 256, 0, stream>>>(P, A, csr, ptr, stats0, nullptr, nullptr);
    bn_relu<<<N * 16 / 256, 256, 0, stream>>>((float4*)A, stats0, g0, be0);

    // ---- layer 1 ----
    proj<64><<<1024, 256, 0, stream>>>(A, Wrel1, Wroot1, b1, P, A);
    gather<0><<<1024, 256, 0, stream>>>(P, A, csr, ptr, stats1, nullptr, nullptr);
    bn_relu<<<N * 16 / 256, 256, 0, stream>>>((float4*)A, stats1, g1, be1);

    // ---- layer 2 + pooling ----
    proj<64><<<1024, 256, 0, stream>>>(A, Wrel2, Wroot2, b2, P, A);
    gather<1><<<1024, 256, 0, stream>>>(P, A, csr, ptr, nullptr, batch, pool);

    // ---- head ----
    head<<<G, 64, 0, stream>>>(pool, batch, Wl1, bl1, Wl2, bl2, (float*)d_out);
}

// Round 3
// 816.495 us; speedup vs baseline: 2.1156x; 1.2339x over previous
//
#include <hip/hip_runtime.h>

constexpr int N   = 100000;
constexpr int E   = 1600000;
constexpr int FIN = 9;
constexpr int OUTF = 6;
constexpr int G   = 1024;
constexpr int SCAN_B = 1024;
constexpr int NBLK = (N + SCAN_B - 1) / SCAN_B;   // 98

__device__ __forceinline__ void atomAddF(float* p, float v) { unsafeAtomicAdd(p, v); }

// ---- CSR build: histogram of dst ----
__global__ __launch_bounds__(256) void hist(const int* __restrict__ dst, int* __restrict__ deg)
{
    int i = blockIdx.x * blockDim.x + threadIdx.x, s = gridDim.x * blockDim.x;
    for (int e = i; e < E; e += s) atomicAdd(&deg[dst[e]], 1);
}

__global__ __launch_bounds__(SCAN_B) void blocksum(const int* __restrict__ deg, int* __restrict__ bsum)
{
    __shared__ int sm[SCAN_B];
    int t = threadIdx.x, idx = blockIdx.x * SCAN_B + t;
    sm[t] = (idx < N) ? deg[idx] : 0;
    __syncthreads();
    for (int o = SCAN_B / 2; o > 0; o >>= 1) { if (t < o) sm[t] += sm[t + o]; __syncthreads(); }
    if (t == 0) bsum[blockIdx.x] = sm[0];
}

__global__ void scanbsum(const int* __restrict__ bsum, int* __restrict__ boff)
{
    if (threadIdx.x == 0) {
        int acc = 0;
        for (int b = 0; b < NBLK; b++) { boff[b] = acc; acc += bsum[b]; }
    }
}

__global__ __launch_bounds__(SCAN_B) void scanwrite(const int* __restrict__ deg,
    const int* __restrict__ boff, int* __restrict__ ptr, int* __restrict__ pos)
{
    __shared__ int sm[SCAN_B];
    int t = threadIdx.x, idx = blockIdx.x * SCAN_B + t;
    int v = (idx < N) ? deg[idx] : 0;
    sm[t] = v;
    __syncthreads();
    for (int o = 1; o < SCAN_B; o <<= 1) {
        int add = (t >= o) ? sm[t - o] : 0;
        __syncthreads();
        sm[t] += add;
        __syncthreads();
    }
    int excl = sm[t] - v + boff[blockIdx.x];
    if (idx < N) { ptr[idx] = excl; pos[idx] = excl; }
    if (idx == N - 1) ptr[N] = excl + v;
}

__global__ __launch_bounds__(256) void fillcsr(const int* __restrict__ src, const int* __restrict__ dst,
    const float* __restrict__ ew, int* __restrict__ pos, int2* __restrict__ csr)
{
    int i = blockIdx.x * blockDim.x + threadIdx.x, s = gridDim.x * blockDim.x;
    for (int e = i; e < E; e += s) {
        int d = dst[e];
        int p = atomicAdd(&pos[d], 1);
        csr[p] = make_int2(src[e], __float_as_int(ew[e]));
    }
}

// ---- fused projection: P = Ain@Wrel ; Aout = Ain@Wroot + b (Aout may alias Ain) ----
template<int K>
__global__ __launch_bounds__(256) void proj(const float* Ain,
    const float* __restrict__ Wrel, const float* __restrict__ Wroot,
    const float* __restrict__ bias, float* __restrict__ P, float* Aout)
{
    int t = threadIdx.x, j = t & 63;
    int nl = __builtin_amdgcn_readfirstlane(t >> 6);   // wave-uniform sub-tile
    float wrel[K], wroot[K];
#pragma unroll
    for (int k = 0; k < K; k++) { wrel[k] = Wrel[k * 64 + j]; wroot[k] = Wroot[k * 64 + j]; }
    float bj = bias[j];
    const int ntiles = N / 4;   // exact
    for (int tile = blockIdx.x; tile < ntiles; tile += gridDim.x) {
        int n = tile * 4 + nl;
        float ap = 0.f, ar = bj;
        if constexpr (K == 64) {
            const float4* r4 = (const float4*)(Ain + (size_t)n * 64);
#pragma unroll
            for (int q = 0; q < 16; q++) {
                float4 v = r4[q];
                ap = fmaf(v.x, wrel[4*q+0], ap); ar = fmaf(v.x, wroot[4*q+0], ar);
                ap = fmaf(v.y, wrel[4*q+1], ap); ar = fmaf(v.y, wroot[4*q+1], ar);
                ap = fmaf(v.z, wrel[4*q+2], ap); ar = fmaf(v.z, wroot[4*q+2], ar);
                ap = fmaf(v.w, wrel[4*q+3], ap); ar = fmaf(v.w, wroot[4*q+3], ar);
            }
        } else {
            const float* r = Ain + (size_t)n * K;
#pragma unroll
            for (int k = 0; k < K; k++) {
                float h = r[k];
                ap = fmaf(h, wrel[k], ap);
                ar = fmaf(h, wroot[k], ar);
            }
        }
        P[(size_t)n * 64 + j] = ap;
        Aout[(size_t)n * 64 + j] = ar;    // all row loads precede store via data dep
    }
}

// ---- gather-aggregate: A[n] += sum_e w_e * P[src_e] ----
// wave per node, lane = feature; edges read at wave-uniform addresses (HW
// broadcast), 4 independent P-row loads in flight per iteration for ILP.
template<int EPI>   // 0: write A + BN stats; 1: pool atomics (A unchanged)
__global__ __launch_bounds__(256) void gather(const float* __restrict__ P, float* A,
    const int2* __restrict__ csr, const int* __restrict__ ptr,
    float* __restrict__ stats, const int* __restrict__ batch, float* __restrict__ pool)
{
    int t = threadIdx.x, lane = t & 63;
    int wv = (blockIdx.x * blockDim.x + t) >> 6;
    int nw = (gridDim.x * blockDim.x) >> 6;
    float s1 = 0.f, s2 = 0.f;
    for (int n = wv; n < N; n += nw) {
        int beg = ptr[n], end = ptr[n + 1];
        float acc0 = A[(size_t)n * 64 + lane];   // root part already in place
        float acc1 = 0.f, acc2 = 0.f, acc3 = 0.f;
        int k = beg;
        for (; k + 4 <= end; k += 4) {
            int2 e0 = csr[k + 0], e1 = csr[k + 1], e2 = csr[k + 2], e3 = csr[k + 3];
            float p0 = P[(size_t)e0.x * 64 + lane];
            float p1 = P[(size_t)e1.x * 64 + lane];
            float p2 = P[(size_t)e2.x * 64 + lane];
            float p3 = P[(size_t)e3.x * 64 + lane];
            acc0 = fmaf(__int_as_float(e0.y), p0, acc0);
            acc1 = fmaf(__int_as_float(e1.y), p1, acc1);
            acc2 = fmaf(__int_as_float(e2.y), p2, acc2);
            acc3 = fmaf(__int_as_float(e3.y), p3, acc3);
        }
        for (; k < end; k++) {
            int2 e = csr[k];
            acc0 = fmaf(__int_as_float(e.y), P[(size_t)e.x * 64 + lane], acc0);
        }
        float acc = (acc0 + acc1) + (acc2 + acc3);
        if constexpr (EPI == 0) {
            A[(size_t)n * 64 + lane] = acc;
            s1 += acc; s2 += acc * acc;
        } else {
            atomAddF(&pool[batch[n] * 64 + lane], acc);
        }
    }
    if constexpr (EPI == 0) {
        __shared__ float sred[256];
        sred[t] = s1; __syncthreads();
        if (t < 64) atomAddF(&stats[t], sred[t] + sred[t+64] + sred[t+128] + sred[t+192]);
        __syncthreads();
        sred[t] = s2; __syncthreads();
        if (t < 64) atomAddF(&stats[64 + t], sred[t] + sred[t+64] + sred[t+128] + sred[t+192]);
    }
}

// ---- BN finalize + ReLU, in place, float4 ----
__global__ __launch_bounds__(256) void bn_relu(float4* __restrict__ H4,
    const float* __restrict__ stats, const float* __restrict__ gam, const float* __restrict__ bet)
{
    int i = blockIdx.x * blockDim.x + threadIdx.x;   // over N*16 exactly
    constexpr float invN = 1.0f / (float)N;
    int j0 = (i & 15) * 4;
    float4 h = H4[i];
    float r[4] = {h.x, h.y, h.z, h.w};
#pragma unroll
    for (int c = 0; c < 4; c++) {
        int j = j0 + c;
        float m  = stats[j] * invN;
        float vv = stats[64 + j] * invN - m * m;
        float sc = gam[j] * rsqrtf(vv + 1e-5f);
        float sh = bet[j] - m * sc;
        r[c] = fmaxf(fmaf(r[c], sc, sh), 0.f);
    }
    H4[i] = make_float4(r[0], r[1], r[2], r[3]);
}

// ---- head: mean-pool finalize + 2-layer MLP ----
__global__ __launch_bounds__(64) void head(const float* __restrict__ pool,
    const int* __restrict__ batch, const float* __restrict__ Wl1, const float* __restrict__ bl1,
    const float* __restrict__ Wl2, const float* __restrict__ bl2, float* __restrict__ out)
{
    int g = blockIdx.x, t = threadIdx.x;
    __shared__ float sp[64];
    __shared__ float sz[64];
    __shared__ int scnt;
    if (t == 0) {
        int lo = 0, hi = N;
        while (lo < hi) { int m = (lo + hi) >> 1; if (batch[m] < g) lo = m + 1; else hi = m; }
        int lo2 = lo, hi2 = N;
        while (lo2 < hi2) { int m = (lo2 + hi2) >> 1; if (batch[m] < g + 1) lo2 = m + 1; else hi2 = m; }
        scnt = lo2 - lo;
    }
    __syncthreads();
    float cnt = fmaxf((float)scnt, 1.0f);
    sp[t] = pool[g * 64 + t] / cnt;
    __syncthreads();
    float acc = bl1[t];
#pragma unroll
    for (int k = 0; k < 64; k++) acc = fmaf(sp[k], Wl1[k * 64 + t], acc);
    sz[t] = fmaxf(acc, 0.f);
    __syncthreads();
    if (t < OUTF) {
        float o = bl2[t];
#pragma unroll
        for (int k = 0; k < 64; k++) o = fmaf(sz[k], Wl2[k * OUTF + t], o);
        out[g * OUTF + t] = o;
    }
}

extern "C" void kernel_launch(void* const* d_in, const int* in_sizes, int n_in,
                              void* d_out, int out_size, void* d_ws, size_t ws_size,
                              hipStream_t stream)
{
    const float* x     = (const float*)d_in[0];
    const int*   ei    = (const int*)d_in[1];
    const float* ew    = (const float*)d_in[2];
    const int*   batch = (const int*)d_in[3];
    const float* Wrel0 = (const float*)d_in[4];
    const float* Wroot0= (const float*)d_in[5];
    const float* b0    = (const float*)d_in[6];
    const float* Wrel1 = (const float*)d_in[7];
    const float* Wroot1= (const float*)d_in[8];
    const float* b1    = (const float*)d_in[9];
    const float* Wrel2 = (const float*)d_in[10];
    const float* Wroot2= (const float*)d_in[11];
    const float* b2    = (const float*)d_in[12];
    const float* g0    = (const float*)d_in[13];
    const float* be0   = (const float*)d_in[14];
    const float* g1    = (const float*)d_in[15];
    const float* be1   = (const float*)d_in[16];
    const float* Wl1   = (const float*)d_in[17];
    const float* bl1   = (const float*)d_in[18];
    const float* Wl2   = (const float*)d_in[19];
    const float* bl2   = (const float*)d_in[20];
    const int* srcI = ei;
    const int* dstI = ei + E;

    float* ws = (float*)d_ws;
    float* A      = ws;                              // N*64
    float* P      = A + (size_t)N * 64;              // N*64
    int2*  csr    = (int2*)(P + (size_t)N * 64);     // E pairs
    int*   ptr    = (int*)(csr + E);                 // N+1
    int*   pos    = ptr + N + 1;                     // N
    int*   deg    = pos + N;                         // N
    int*   bsum   = deg + N;                         // NBLK
    int*   boff   = bsum + NBLK;                     // NBLK
    float* stats0 = (float*)(boff + NBLK);           // 128
    float* stats1 = stats0 + 128;                    // 128
    float* pool   = stats1 + 128;                    // G*64

    hipMemsetAsync(deg, 0, (size_t)N * sizeof(int), stream);
    hipMemsetAsync(stats0, 0, (size_t)(256 + G * 64) * sizeof(float), stream);

    // ---- CSR build (by dst), reused by all 3 layers ----
    hist<<<2048, 256, 0, stream>>>(dstI, deg);
    blocksum<<<NBLK, SCAN_B, 0, stream>>>(deg, bsum);
    scanbsum<<<1, 64, 0, stream>>>(bsum, boff);
    scanwrite<<<NBLK, SCAN_B, 0, stream>>>(deg, boff, ptr, pos);
    fillcsr<<<2048, 256, 0, stream>>>(srcI, dstI, ew, pos, csr);

    // ---- layer 0 ----
    proj<FIN><<<1024, 256, 0, stream>>>(x, Wrel0, Wroot0, b0, P, A);
    gather<0><<<2048, 256, 0, stream>>>(P, A, csr, ptr, stats0, nullptr, nullptr);
    bn_relu<<<N * 16 / 256, 256, 0, stream>>>((float4*)A, stats0, g0, be0);

    // ---- layer 1 ----
    proj<64><<<1024, 256, 0, stream>>>(A, Wrel1, Wroot1, b1, P, A);
    gather<0><<<2048, 256, 0, stream>>>(P, A, csr, ptr, stats1, nullptr, nullptr);
    bn_relu<<<N * 16 / 256, 256, 0, stream>>>((float4*)A, stats1, g1, be1);

    // ---- layer 2 + pooling ----
    proj<64><<<1024, 256, 0, stream>>>(A, Wrel2, Wroot2, b2, P, A);
    gather<1><<<2048, 256, 0, stream>>>(P, A, csr, ptr, nullptr, batch, pool);

    // ---- head ----
    head<<<G, 64, 0, stream>>>(pool, batch, Wl1, bl1, Wl2, bl2, (float*)d_out);
}

// Round 4
// 696.158 us; speedup vs baseline: 2.4813x; 1.1729x over previous
//
#include <hip/hip_runtime.h>

constexpr int N    = 100000;
constexpr int E    = 1600000;
constexpr int FIN  = 9;
constexpr int OUTF = 6;
constexpr int G    = 1024;
constexpr int NPB  = 256;                    // nodes per bucket
constexpr int NB   = (N + NPB - 1) / NPB;    // 391 buckets
constexpr int CH   = 2048;                   // edges per chunk
constexpr int NCH  = (E + CH - 1) / CH;      // 782

__device__ __forceinline__ void atomAddF(float* p, float v) { unsafeAtomicAdd(p, v); }

// ---- CSR build step 1: bucket histogram (dst>>8) ----
__global__ __launch_bounds__(256) void histB(const int* __restrict__ dst, int* __restrict__ gcnt)
{
    __shared__ int h[NB];
    int t = threadIdx.x;
    for (int i = t; i < NB; i += 256) h[i] = 0;
    __syncthreads();
    int base = blockIdx.x * CH;
#pragma unroll
    for (int i = 0; i < 8; i++) {
        int e = base + i * 256 + t;
        if (e < E) atomicAdd(&h[dst[e] >> 8], 1);
    }
    __syncthreads();
    for (int i = t; i < NB; i += 256) if (h[i]) atomicAdd(&gcnt[i], h[i]);
}

// ---- step 2: scan bucket counts -> bucketStart + write cursor; ptr[N]=E ----
__global__ __launch_bounds__(512) void scanB(const int* __restrict__ gcnt,
    int* __restrict__ bstart, int* __restrict__ cursor, int* __restrict__ ptr)
{
    __shared__ int sa[512], sb[512];
    int t = threadIdx.x;
    int v0 = (t < NB) ? gcnt[t] : 0;
    sa[t] = v0;
    __syncthreads();
    int* cur = sa; int* nxt = sb;
    for (int o = 1; o < 512; o <<= 1) {
        int v = cur[t];
        if (t >= o) v += cur[t - o];
        nxt[t] = v;
        __syncthreads();
        int* tmp = cur; cur = nxt; nxt = tmp;
    }
    if (t < NB) { int ex = cur[t] - v0; bstart[t] = ex; cursor[t] = ex; }
    if (t == 0) ptr[N] = E;
}

// ---- step 3: scatter edges into bucket-grouped array (compact tails -> line merging) ----
__global__ __launch_bounds__(256) void passA(const int* __restrict__ src, const int* __restrict__ dst,
    const float* __restrict__ ew, int* __restrict__ cursor, int4* __restrict__ bucketed)
{
    __shared__ int h[NB];
    __shared__ int hb[NB];
    int t = threadIdx.x;
    for (int i = t; i < NB; i += 256) h[i] = 0;
    __syncthreads();
    int base = blockIdx.x * CH;
    int myS[8], myD[8], rk[8]; float myW[8];
#pragma unroll
    for (int i = 0; i < 8; i++) {
        int e = base + i * 256 + t;
        if (e < E) {
            myS[i] = src[e]; myD[i] = dst[e]; myW[i] = ew[e];
            rk[i] = atomicAdd(&h[myD[i] >> 8], 1);
        } else myD[i] = -1;
    }
    __syncthreads();
    for (int i = t; i < NB; i += 256) hb[i] = h[i] ? atomicAdd(&cursor[i], h[i]) : 0;
    __syncthreads();
#pragma unroll
    for (int i = 0; i < 8; i++) if (myD[i] >= 0)
        bucketed[hb[myD[i] >> 8] + rk[i]] = make_int4(myS[i], myD[i], __float_as_int(myW[i]), 0);
}

// ---- step 4: per-bucket local CSR (hist + scan + compact scatter, all in a 32KB window) ----
__global__ __launch_bounds__(NPB) void passB(const int* __restrict__ gcnt, const int* __restrict__ bstart,
    int4* __restrict__ bucketed, int* __restrict__ ptr, int2* __restrict__ csr)
{
    int b = blockIdx.x, t = threadIdx.x;
    int node0 = b * NPB;
    int nnode = min(NPB, N - node0);
    int cnt = gcnt[b], base = bstart[b];
    __shared__ int cl[NPB], sa[NPB], sb[NPB];
    cl[t] = 0;
    __syncthreads();
    for (int e = t; e < cnt; e += NPB) {          // hist + per-node rank
        int4 r = bucketed[base + e];
        int rk = atomicAdd(&cl[r.y - node0], 1);
        bucketed[base + e].w = rk;
    }
    __syncthreads();
    int* cur = sa; int* nxt = sb;
    cur[t] = cl[t];
    __syncthreads();
    for (int o = 1; o < NPB; o <<= 1) {           // inclusive scan
        int v = cur[t];
        if (t >= o) v += cur[t - o];
        nxt[t] = v;
        __syncthreads();
        int* tmp = cur; cur = nxt; nxt = tmp;
    }
    int excl = cur[t] - cl[t];
    if (t < nnode) ptr[node0 + t] = base + excl;
    nxt[t] = excl;
    __syncthreads();
    for (int e = t; e < cnt; e += NPB) {
        int4 r = bucketed[base + e];
        int pos = base + nxt[r.y - node0] + r.w;
        csr[pos] = make_int2(r.x, r.z);
    }
}

// ---- fused projection: P = Ain@Wrel ; Aout = Ain@Wroot + b (Aout may alias Ain) ----
template<int K>
__global__ __launch_bounds__(256) void proj(const float* Ain,
    const float* __restrict__ Wrel, const float* __restrict__ Wroot,
    const float* __restrict__ bias, float* __restrict__ P, float* Aout)
{
    int t = threadIdx.x, j = t & 63;
    int nl = __builtin_amdgcn_readfirstlane(t >> 6);   // wave-uniform sub-tile
    float wrel[K], wroot[K];
#pragma unroll
    for (int k = 0; k < K; k++) { wrel[k] = Wrel[k * 64 + j]; wroot[k] = Wroot[k * 64 + j]; }
    float bj = bias[j];
    const int ntiles = N / 4;   // exact
    for (int tile = blockIdx.x; tile < ntiles; tile += gridDim.x) {
        int n = tile * 4 + nl;
        float ap = 0.f, ar = bj;
        if constexpr (K == 64) {
            const float4* r4 = (const float4*)(Ain + (size_t)n * 64);
#pragma unroll
            for (int q = 0; q < 16; q++) {
                float4 v = r4[q];
                ap = fmaf(v.x, wrel[4*q+0], ap); ar = fmaf(v.x, wroot[4*q+0], ar);
                ap = fmaf(v.y, wrel[4*q+1], ap); ar = fmaf(v.y, wroot[4*q+1], ar);
                ap = fmaf(v.z, wrel[4*q+2], ap); ar = fmaf(v.z, wroot[4*q+2], ar);
                ap = fmaf(v.w, wrel[4*q+3], ap); ar = fmaf(v.w, wroot[4*q+3], ar);
            }
        } else {
            const float* r = Ain + (size_t)n * K;
#pragma unroll
            for (int k = 0; k < K; k++) {
                float h = r[k];
                ap = fmaf(h, wrel[k], ap);
                ar = fmaf(h, wroot[k], ar);
            }
        }
        P[(size_t)n * 64 + j] = ap;
        Aout[(size_t)n * 64 + j] = ar;
    }
}

// ---- gather-aggregate: A[n] += sum_e w_e * P[src_e] ----
// wave/node, lane=feature; 4x int4 edge loads + 8 independent P loads per iter.
template<int EPI>   // 0: write A + BN stats; 1: pool atomics
__global__ __launch_bounds__(256) void gather(const float* __restrict__ P, float* A,
    const int2* __restrict__ csr, const int* __restrict__ ptr,
    float* __restrict__ stats, const int* __restrict__ batch, float* __restrict__ pool)
{
    int t = threadIdx.x, lane = t & 63;
    int wv = (blockIdx.x * blockDim.x + t) >> 6;
    int nw = (gridDim.x * blockDim.x) >> 6;
    float s1 = 0.f, s2 = 0.f;
    for (int n = wv; n < N; n += nw) {
        int beg = ptr[n], end = ptr[n + 1];
        float acc0 = A[(size_t)n * 64 + lane];
        float acc1 = 0.f, acc2 = 0.f, acc3 = 0.f;
        float acc4 = 0.f, acc5 = 0.f, acc6 = 0.f, acc7 = 0.f;
        int k = beg;
        if ((k & 1) && k < end) {                    // align to int4
            int2 e = csr[k];
            acc1 = fmaf(__int_as_float(e.y), P[(size_t)e.x * 64 + lane], acc1);
            k++;
        }
        for (; k + 8 <= end; k += 8) {
            const int4* q = (const int4*)(csr + k);  // 16B-aligned: k even
            int4 q0 = q[0], q1 = q[1], q2 = q[2], q3 = q[3];
            float p0 = P[(size_t)q0.x * 64 + lane];
            float p1 = P[(size_t)q0.z * 64 + lane];
            float p2 = P[(size_t)q1.x * 64 + lane];
            float p3 = P[(size_t)q1.z * 64 + lane];
            float p4 = P[(size_t)q2.x * 64 + lane];
            float p5 = P[(size_t)q2.z * 64 + lane];
            float p6 = P[(size_t)q3.x * 64 + lane];
            float p7 = P[(size_t)q3.z * 64 + lane];
            acc0 = fmaf(__int_as_float(q0.y), p0, acc0);
            acc1 = fmaf(__int_as_float(q0.w), p1, acc1);
            acc2 = fmaf(__int_as_float(q1.y), p2, acc2);
            acc3 = fmaf(__int_as_float(q1.w), p3, acc3);
            acc4 = fmaf(__int_as_float(q2.y), p4, acc4);
            acc5 = fmaf(__int_as_float(q2.w), p5, acc5);
            acc6 = fmaf(__int_as_float(q3.y), p6, acc6);
            acc7 = fmaf(__int_as_float(q3.w), p7, acc7);
        }
        for (; k < end; k++) {
            int2 e = csr[k];
            acc0 = fmaf(__int_as_float(e.y), P[(size_t)e.x * 64 + lane], acc0);
        }
        float acc = ((acc0 + acc1) + (acc2 + acc3)) + ((acc4 + acc5) + (acc6 + acc7));
        if constexpr (EPI == 0) {
            A[(size_t)n * 64 + lane] = acc;
            s1 += acc; s2 += acc * acc;
        } else {
            atomAddF(&pool[batch[n] * 64 + lane], acc);
        }
    }
    if constexpr (EPI == 0) {
        __shared__ float sred[256];
        sred[t] = s1; __syncthreads();
        if (t < 64) atomAddF(&stats[t], sred[t] + sred[t+64] + sred[t+128] + sred[t+192]);
        __syncthreads();
        sred[t] = s2; __syncthreads();
        if (t < 64) atomAddF(&stats[64 + t], sred[t] + sred[t+64] + sred[t+128] + sred[t+192]);
    }
}

// ---- BN finalize + ReLU, in place, float4 ----
__global__ __launch_bounds__(256) void bn_relu(float4* __restrict__ H4,
    const float* __restrict__ stats, const float* __restrict__ gam, const float* __restrict__ bet)
{
    int i = blockIdx.x * blockDim.x + threadIdx.x;
    constexpr float invN = 1.0f / (float)N;
    int j0 = (i & 15) * 4;
    float4 h = H4[i];
    float r[4] = {h.x, h.y, h.z, h.w};
#pragma unroll
    for (int c = 0; c < 4; c++) {
        int j = j0 + c;
        float m  = stats[j] * invN;
        float vv = stats[64 + j] * invN - m * m;
        float sc = gam[j] * rsqrtf(vv + 1e-5f);
        float sh = bet[j] - m * sc;
        r[c] = fmaxf(fmaf(r[c], sc, sh), 0.f);
    }
    H4[i] = make_float4(r[0], r[1], r[2], r[3]);
}

// ---- head: mean-pool finalize + 2-layer MLP ----
__global__ __launch_bounds__(64) void head(const float* __restrict__ pool,
    const int* __restrict__ batch, const float* __restrict__ Wl1, const float* __restrict__ bl1,
    const float* __restrict__ Wl2, const float* __restrict__ bl2, float* __restrict__ out)
{
    int g = blockIdx.x, t = threadIdx.x;
    __shared__ float sp[64];
    __shared__ float sz[64];
    __shared__ int scnt;
    if (t == 0) {
        int lo = 0, hi = N;
        while (lo < hi) { int m = (lo + hi) >> 1; if (batch[m] < g) lo = m + 1; else hi = m; }
        int lo2 = lo, hi2 = N;
        while (lo2 < hi2) { int m = (lo2 + hi2) >> 1; if (batch[m] < g + 1) lo2 = m + 1; else hi2 = m; }
        scnt = lo2 - lo;
    }
    __syncthreads();
    float cnt = fmaxf((float)scnt, 1.0f);
    sp[t] = pool[g * 64 + t] / cnt;
    __syncthreads();
    float acc = bl1[t];
#pragma unroll
    for (int k = 0; k < 64; k++) acc = fmaf(sp[k], Wl1[k * 64 + t], acc);
    sz[t] = fmaxf(acc, 0.f);
    __syncthreads();
    if (t < OUTF) {
        float o = bl2[t];
#pragma unroll
        for (int k = 0; k < 64; k++) o = fmaf(sz[k], Wl2[k * OUTF + t], o);
        out[g * OUTF + t] = o;
    }
}

extern "C" void kernel_launch(void* const* d_in, const int* in_sizes, int n_in,
                              void* d_out, int out_size, void* d_ws, size_t ws_size,
                              hipStream_t stream)
{
    const float* x     = (const float*)d_in[0];
    const int*   ei    = (const int*)d_in[1];
    const float* ew    = (const float*)d_in[2];
    const int*   batch = (const int*)d_in[3];
    const float* Wrel0 = (const float*)d_in[4];
    const float* Wroot0= (const float*)d_in[5];
    const float* b0    = (const float*)d_in[6];
    const float* Wrel1 = (const float*)d_in[7];
    const float* Wroot1= (const float*)d_in[8];
    const float* b1    = (const float*)d_in[9];
    const float* Wrel2 = (const float*)d_in[10];
    const float* Wroot2= (const float*)d_in[11];
    const float* b2    = (const float*)d_in[12];
    const float* g0    = (const float*)d_in[13];
    const float* be0   = (const float*)d_in[14];
    const float* g1    = (const float*)d_in[15];
    const float* be1   = (const float*)d_in[16];
    const float* Wl1   = (const float*)d_in[17];
    const float* bl1   = (const float*)d_in[18];
    const float* Wl2   = (const float*)d_in[19];
    const float* bl2   = (const float*)d_in[20];
    const int* srcI = ei;
    const int* dstI = ei + E;

    float* ws = (float*)d_ws;
    float* A      = ws;                              // N*64 f32
    float* P      = A + (size_t)N * 64;              // N*64 f32
    int4*  bucketed = (int4*)P;                      // E int4 = 25.6MB, aliases P (dead until proj)
    int2*  csr    = (int2*)(P + (size_t)N * 64);     // E int2
    int*   ptr    = (int*)(csr + E);                 // N+1
    int*   gcnt   = ptr + N + 1;                     // NB
    int*   bstart = gcnt + NB;                       // NB
    int*   cursor = bstart + NB;                     // NB
    float* stats0 = (float*)(cursor + NB);           // 128
    float* stats1 = stats0 + 128;                    // 128
    float* pool   = stats1 + 128;                    // G*64

    hipMemsetAsync(gcnt, 0, (size_t)NB * sizeof(int), stream);
    hipMemsetAsync(stats0, 0, (size_t)(256 + G * 64) * sizeof(float), stream);

    // ---- CSR build (bucketed, by dst) ----
    histB<<<NCH, 256, 0, stream>>>(dstI, gcnt);
    scanB<<<1, 512, 0, stream>>>(gcnt, bstart, cursor, ptr);
    passA<<<NCH, 256, 0, stream>>>(srcI, dstI, ew, cursor, bucketed);
    passB<<<NB, NPB, 0, stream>>>(gcnt, bstart, bucketed, ptr, csr);

    // ---- layer 0 ----
    proj<FIN><<<2048, 256, 0, stream>>>(x, Wrel0, Wroot0, b0, P, A);
    gather<0><<<2048, 256, 0, stream>>>(P, A, csr, ptr, stats0, nullptr, nullptr);
    bn_relu<<<N * 16 / 256, 256, 0, stream>>>((float4*)A, stats0, g0, be0);

    // ---- layer 1 ----
    proj<64><<<2048, 256, 0, stream>>>(A, Wrel1, Wroot1, b1, P, A);
    gather<0><<<2048, 256, 0, stream>>>(P, A, csr, ptr, stats1, nullptr, nullptr);
    bn_relu<<<N * 16 / 256, 256, 0, stream>>>((float4*)A, stats1, g1, be1);

    // ---- layer 2 + pooling ----
    proj<64><<<2048, 256, 0, stream>>>(A, Wrel2, Wroot2, b2, P, A);
    gather<1><<<2048, 256, 0, stream>>>(P, A, csr, ptr, nullptr, batch, pool);

    // ---- head ----
    head<<<G, 64, 0, stream>>>(pool, batch, Wl1, bl1, Wl2, bl2, (float*)d_out);
}

// Round 5
// 675.290 us; speedup vs baseline: 2.5579x; 1.0309x over previous
//
#include <hip/hip_runtime.h>
#include <hip/hip_fp16.h>

constexpr int N    = 100000;
constexpr int E    = 1600000;
constexpr int FIN  = 9;
constexpr int OUTF = 6;
constexpr int G    = 1024;
constexpr int NPB  = 256;                    // nodes per bucket
constexpr int NB   = (N + NPB - 1) / NPB;    // 391 buckets
constexpr int CH   = 2048;                   // edges per chunk
constexpr int NCH  = (E + CH - 1) / CH;      // 782

__device__ __forceinline__ void atomAddF(float* p, float v) { unsafeAtomicAdd(p, v); }

// ---- CSR build step 1: bucket histogram (dst>>8) ----
__global__ __launch_bounds__(256) void histB(const int* __restrict__ dst, int* __restrict__ gcnt)
{
    __shared__ int h[NB];
    int t = threadIdx.x;
    for (int i = t; i < NB; i += 256) h[i] = 0;
    __syncthreads();
    int base = blockIdx.x * CH;
#pragma unroll
    for (int i = 0; i < 8; i++) {
        int e = base + i * 256 + t;
        if (e < E) atomicAdd(&h[dst[e] >> 8], 1);
    }
    __syncthreads();
    for (int i = t; i < NB; i += 256) if (h[i]) atomicAdd(&gcnt[i], h[i]);
}

// ---- step 2: scan bucket counts -> bucketStart + write cursor; ptr[N]=E ----
__global__ __launch_bounds__(512) void scanB(const int* __restrict__ gcnt,
    int* __restrict__ bstart, int* __restrict__ cursor, int* __restrict__ ptr)
{
    __shared__ int sa[512], sb[512];
    int t = threadIdx.x;
    int v0 = (t < NB) ? gcnt[t] : 0;
    sa[t] = v0;
    __syncthreads();
    int* cur = sa; int* nxt = sb;
    for (int o = 1; o < 512; o <<= 1) {
        int v = cur[t];
        if (t >= o) v += cur[t - o];
        nxt[t] = v;
        __syncthreads();
        int* tmp = cur; cur = nxt; nxt = tmp;
    }
    if (t < NB) { int ex = cur[t] - v0; bstart[t] = ex; cursor[t] = ex; }
    if (t == 0) ptr[N] = E;
}

// ---- step 3: scatter edges into bucket-grouped array ----
__global__ __launch_bounds__(256) void passA(const int* __restrict__ src, const int* __restrict__ dst,
    const float* __restrict__ ew, int* __restrict__ cursor, int4* __restrict__ bucketed)
{
    __shared__ int h[NB];
    __shared__ int hb[NB];
    int t = threadIdx.x;
    for (int i = t; i < NB; i += 256) h[i] = 0;
    __syncthreads();
    int base = blockIdx.x * CH;
    int myS[8], myD[8], rk[8]; float myW[8];
#pragma unroll
    for (int i = 0; i < 8; i++) {
        int e = base + i * 256 + t;
        if (e < E) {
            myS[i] = src[e]; myD[i] = dst[e]; myW[i] = ew[e];
            rk[i] = atomicAdd(&h[myD[i] >> 8], 1);
        } else myD[i] = -1;
    }
    __syncthreads();
    for (int i = t; i < NB; i += 256) hb[i] = h[i] ? atomicAdd(&cursor[i], h[i]) : 0;
    __syncthreads();
#pragma unroll
    for (int i = 0; i < 8; i++) if (myD[i] >= 0)
        bucketed[hb[myD[i] >> 8] + rk[i]] = make_int4(myS[i], myD[i], __float_as_int(myW[i]), 0);
}

// ---- step 4: per-bucket local CSR ----
__global__ __launch_bounds__(NPB) void passB(const int* __restrict__ gcnt, const int* __restrict__ bstart,
    int4* __restrict__ bucketed, int* __restrict__ ptr, int2* __restrict__ csr)
{
    int b = blockIdx.x, t = threadIdx.x;
    int node0 = b * NPB;
    int nnode = min(NPB, N - node0);
    int cnt = gcnt[b], base = bstart[b];
    __shared__ int cl[NPB], sa[NPB], sb[NPB];
    cl[t] = 0;
    __syncthreads();
    for (int e = t; e < cnt; e += NPB) {
        int4 r = bucketed[base + e];
        int rk = atomicAdd(&cl[r.y - node0], 1);
        bucketed[base + e].w = rk;
    }
    __syncthreads();
    int* cur = sa; int* nxt = sb;
    cur[t] = cl[t];
    __syncthreads();
    for (int o = 1; o < NPB; o <<= 1) {
        int v = cur[t];
        if (t >= o) v += cur[t - o];
        nxt[t] = v;
        __syncthreads();
        int* tmp = cur; cur = nxt; nxt = tmp;
    }
    int excl = cur[t] - cl[t];
    if (t < nnode) ptr[node0 + t] = base + excl;
    nxt[t] = excl;
    __syncthreads();
    for (int e = t; e < cnt; e += NPB) {
        int4 r = bucketed[base + e];
        int pos = base + nxt[r.y - node0] + r.w;
        csr[pos] = make_int2(r.x, r.z);
    }
}

// ---- fused projection: P(fp16) = Ain@Wrel ; Aout = Ain@Wroot + b (Aout may alias Ain) ----
template<int K>
__global__ __launch_bounds__(256) void proj(const float* Ain,
    const float* __restrict__ Wrel, const float* __restrict__ Wroot,
    const float* __restrict__ bias, __half* __restrict__ P, float* Aout)
{
    int t = threadIdx.x, j = t & 63;
    int nl = __builtin_amdgcn_readfirstlane(t >> 6);   // wave-uniform sub-tile
    float wrel[K], wroot[K];
#pragma unroll
    for (int k = 0; k < K; k++) { wrel[k] = Wrel[k * 64 + j]; wroot[k] = Wroot[k * 64 + j]; }
    float bj = bias[j];
    const int ntiles = N / 4;   // exact
    for (int tile = blockIdx.x; tile < ntiles; tile += gridDim.x) {
        int n = tile * 4 + nl;
        float ap = 0.f, ar = bj;
        if constexpr (K == 64) {
            const float4* r4 = (const float4*)(Ain + (size_t)n * 64);
#pragma unroll
            for (int q = 0; q < 16; q++) {
                float4 v = r4[q];
                ap = fmaf(v.x, wrel[4*q+0], ap); ar = fmaf(v.x, wroot[4*q+0], ar);
                ap = fmaf(v.y, wrel[4*q+1], ap); ar = fmaf(v.y, wroot[4*q+1], ar);
                ap = fmaf(v.z, wrel[4*q+2], ap); ar = fmaf(v.z, wroot[4*q+2], ar);
                ap = fmaf(v.w, wrel[4*q+3], ap); ar = fmaf(v.w, wroot[4*q+3], ar);
            }
        } else {
            const float* r = Ain + (size_t)n * K;
#pragma unroll
            for (int k = 0; k < K; k++) {
                float h = r[k];
                ap = fmaf(h, wrel[k], ap);
                ar = fmaf(h, wroot[k], ar);
            }
        }
        P[(size_t)n * 64 + j] = __float2half(ap);
        Aout[(size_t)n * 64 + j] = ar;
    }
}

// ---- gather-aggregate: A[n] += sum_e w_e * P[src_e]  (P in fp16: 128B rows) ----
template<int EPI>   // 0: write A + BN stats; 1: pool atomics
__global__ __launch_bounds__(256) void gather(const __half* __restrict__ P, float* A,
    const int2* __restrict__ csr, const int* __restrict__ ptr,
    float* __restrict__ stats, const int* __restrict__ batch, float* __restrict__ pool)
{
    int t = threadIdx.x, lane = t & 63;
    int wv = (blockIdx.x * blockDim.x + t) >> 6;
    int nw = (gridDim.x * blockDim.x) >> 6;
    float s1 = 0.f, s2 = 0.f;
    for (int n = wv; n < N; n += nw) {
        int beg = ptr[n], end = ptr[n + 1];
        float acc0 = A[(size_t)n * 64 + lane];
        float acc1 = 0.f, acc2 = 0.f, acc3 = 0.f;
        float acc4 = 0.f, acc5 = 0.f, acc6 = 0.f, acc7 = 0.f;
        int k = beg;
        if ((k & 1) && k < end) {                    // align to int4
            int2 e = csr[k];
            acc1 = fmaf(__int_as_float(e.y), __half2float(P[(size_t)e.x * 64 + lane]), acc1);
            k++;
        }
        for (; k + 8 <= end; k += 8) {
            const int4* q = (const int4*)(csr + k);  // 16B-aligned: k even
            int4 q0 = q[0], q1 = q[1], q2 = q[2], q3 = q[3];
            float p0 = __half2float(P[(size_t)q0.x * 64 + lane]);
            float p1 = __half2float(P[(size_t)q0.z * 64 + lane]);
            float p2 = __half2float(P[(size_t)q1.x * 64 + lane]);
            float p3 = __half2float(P[(size_t)q1.z * 64 + lane]);
            float p4 = __half2float(P[(size_t)q2.x * 64 + lane]);
            float p5 = __half2float(P[(size_t)q2.z * 64 + lane]);
            float p6 = __half2float(P[(size_t)q3.x * 64 + lane]);
            float p7 = __half2float(P[(size_t)q3.z * 64 + lane]);
            acc0 = fmaf(__int_as_float(q0.y), p0, acc0);
            acc1 = fmaf(__int_as_float(q0.w), p1, acc1);
            acc2 = fmaf(__int_as_float(q1.y), p2, acc2);
            acc3 = fmaf(__int_as_float(q1.w), p3, acc3);
            acc4 = fmaf(__int_as_float(q2.y), p4, acc4);
            acc5 = fmaf(__int_as_float(q2.w), p5, acc5);
            acc6 = fmaf(__int_as_float(q3.y), p6, acc6);
            acc7 = fmaf(__int_as_float(q3.w), p7, acc7);
        }
        for (; k < end; k++) {
            int2 e = csr[k];
            acc0 = fmaf(__int_as_float(e.y), __half2float(P[(size_t)e.x * 64 + lane]), acc0);
        }
        float acc = ((acc0 + acc1) + (acc2 + acc3)) + ((acc4 + acc5) + (acc6 + acc7));
        if constexpr (EPI == 0) {
            A[(size_t)n * 64 + lane] = acc;
            s1 += acc; s2 += acc * acc;
        } else {
            atomAddF(&pool[batch[n] * 64 + lane], acc);
        }
    }
    if constexpr (EPI == 0) {
        __shared__ float sred[256];
        sred[t] = s1; __syncthreads();
        if (t < 64) atomAddF(&stats[t], sred[t] + sred[t+64] + sred[t+128] + sred[t+192]);
        __syncthreads();
        sred[t] = s2; __syncthreads();
        if (t < 64) atomAddF(&stats[64 + t], sred[t] + sred[t+64] + sred[t+128] + sred[t+192]);
    }
}

// ---- BN finalize + ReLU, in place, float4 ----
__global__ __launch_bounds__(256) void bn_relu(float4* __restrict__ H4,
    const float* __restrict__ stats, const float* __restrict__ gam, const float* __restrict__ bet)
{
    int i = blockIdx.x * blockDim.x + threadIdx.x;
    constexpr float invN = 1.0f / (float)N;
    int j0 = (i & 15) * 4;
    float4 h = H4[i];
    float r[4] = {h.x, h.y, h.z, h.w};
#pragma unroll
    for (int c = 0; c < 4; c++) {
        int j = j0 + c;
        float m  = stats[j] * invN;
        float vv = stats[64 + j] * invN - m * m;
        float sc = gam[j] * rsqrtf(vv + 1e-5f);
        float sh = bet[j] - m * sc;
        r[c] = fmaxf(fmaf(r[c], sc, sh), 0.f);
    }
    H4[i] = make_float4(r[0], r[1], r[2], r[3]);
}

// ---- head: mean-pool finalize + 2-layer MLP ----
__global__ __launch_bounds__(64) void head(const float* __restrict__ pool,
    const int* __restrict__ batch, const float* __restrict__ Wl1, const float* __restrict__ bl1,
    const float* __restrict__ Wl2, const float* __restrict__ bl2, float* __restrict__ out)
{
    int g = blockIdx.x, t = threadIdx.x;
    __shared__ float sp[64];
    __shared__ float sz[64];
    __shared__ int scnt;
    if (t == 0) {
        int lo = 0, hi = N;
        while (lo < hi) { int m = (lo + hi) >> 1; if (batch[m] < g) lo = m + 1; else hi = m; }
        int lo2 = lo, hi2 = N;
        while (lo2 < hi2) { int m = (lo2 + hi2) >> 1; if (batch[m] < g + 1) lo2 = m + 1; else hi2 = m; }
        scnt = lo2 - lo;
    }
    __syncthreads();
    float cnt = fmaxf((float)scnt, 1.0f);
    sp[t] = pool[g * 64 + t] / cnt;
    __syncthreads();
    float acc = bl1[t];
#pragma unroll
    for (int k = 0; k < 64; k++) acc = fmaf(sp[k], Wl1[k * 64 + t], acc);
    sz[t] = fmaxf(acc, 0.f);
    __syncthreads();
    if (t < OUTF) {
        float o = bl2[t];
#pragma unroll
        for (int k = 0; k < 64; k++) o = fmaf(sz[k], Wl2[k * OUTF + t], o);
        out[g * OUTF + t] = o;
    }
}

extern "C" void kernel_launch(void* const* d_in, const int* in_sizes, int n_in,
                              void* d_out, int out_size, void* d_ws, size_t ws_size,
                              hipStream_t stream)
{
    const float* x     = (const float*)d_in[0];
    const int*   ei    = (const int*)d_in[1];
    const float* ew    = (const float*)d_in[2];
    const int*   batch = (const int*)d_in[3];
    const float* Wrel0 = (const float*)d_in[4];
    const float* Wroot0= (const float*)d_in[5];
    const float* b0    = (const float*)d_in[6];
    const float* Wrel1 = (const float*)d_in[7];
    const float* Wroot1= (const float*)d_in[8];
    const float* b1    = (const float*)d_in[9];
    const float* Wrel2 = (const float*)d_in[10];
    const float* Wroot2= (const float*)d_in[11];
    const float* b2    = (const float*)d_in[12];
    const float* g0    = (const float*)d_in[13];
    const float* be0   = (const float*)d_in[14];
    const float* g1    = (const float*)d_in[15];
    const float* be1   = (const float*)d_in[16];
    const float* Wl1   = (const float*)d_in[17];
    const float* bl1   = (const float*)d_in[18];
    const float* Wl2   = (const float*)d_in[19];
    const float* bl2   = (const float*)d_in[20];
    const int* srcI = ei;
    const int* dstI = ei + E;

    float* ws = (float*)d_ws;
    float*  A      = ws;                               // N*64 f32 (25.6 MB)
    __half* P      = (__half*)(A + (size_t)N * 64);    // N*64 f16 (12.8 MB)
    int2*   csr    = (int2*)(P + (size_t)N * 64);      // E int2  (12.8 MB)
    int*    ptr    = (int*)(csr + E);                  // N+1
    int*    gcnt   = ptr + N + 1;                      // NB
    int*    bstart = gcnt + NB;                        // NB
    int*    cursor = bstart + NB;                      // NB
    float*  stats0 = (float*)(cursor + NB);            // 128
    float*  stats1 = stats0 + 128;                     // 128
    float*  pool   = stats1 + 128;                     // G*64
    int4*   bucketed = (int4*)A;                       // E int4 = 25.6MB, aliases A (dead until proj0)

    hipMemsetAsync(gcnt, 0, (size_t)NB * sizeof(int), stream);
    hipMemsetAsync(stats0, 0, (size_t)(256 + G * 64) * sizeof(float), stream);

    // ---- CSR build (bucketed, by dst) ----
    histB<<<NCH, 256, 0, stream>>>(dstI, gcnt);
    scanB<<<1, 512, 0, stream>>>(gcnt, bstart, cursor, ptr);
    passA<<<NCH, 256, 0, stream>>>(srcI, dstI, ew, cursor, bucketed);
    passB<<<NB, NPB, 0, stream>>>(gcnt, bstart, bucketed, ptr, csr);

    // ---- layer 0 ----
    proj<FIN><<<2048, 256, 0, stream>>>(x, Wrel0, Wroot0, b0, P, A);
    gather<0><<<2048, 256, 0, stream>>>(P, A, csr, ptr, stats0, nullptr, nullptr);
    bn_relu<<<N * 16 / 256, 256, 0, stream>>>((float4*)A, stats0, g0, be0);

    // ---- layer 1 ----
    proj<64><<<2048, 256, 0, stream>>>(A, Wrel1, Wroot1, b1, P, A);
    gather<0><<<2048, 256, 0, stream>>>(P, A, csr, ptr, stats1, nullptr, nullptr);
    bn_relu<<<N * 16 / 256, 256, 0, stream>>>((float4*)A, stats1, g1, be1);

    // ---- layer 2 + pooling ----
    proj<64><<<2048, 256, 0, stream>>>(A, Wrel2, Wroot2, b2, P, A);
    gather<1><<<2048, 256, 0, stream>>>(P, A, csr, ptr, nullptr, batch, pool);

    // ---- head ----
    head<<<G, 64, 0, stream>>>(pool, batch, Wl1, bl1, Wl2, bl2, (float*)d_out);
}